// Round 1
// baseline (202.570 us; speedup 1.0000x reference)
//
#include <hip/hip_runtime.h>
#include <hip/hip_bf16.h>

#define NB   4
#define CCH  256
#define CQK  32
#define NTOK 4096

typedef unsigned short u16;
typedef __attribute__((ext_vector_type(8))) __bf16 bf16x8;
typedef __attribute__((ext_vector_type(4))) float  f32x4;

static __device__ __forceinline__ unsigned int f2bf2(float a, float b) {
  union { __hip_bfloat162 h; unsigned int u; } cv;
  cv.h = __float22bfloat162_rn(make_float2(a, b));
  return cv.u;
}

static __device__ __forceinline__ f32x4 mfma16(bf16x8 a, bf16x8 b, f32x4 c) {
  return __builtin_amdgcn_mfma_f32_16x16x32_bf16(a, b, c, 0, 0, 0);
}

// ---------------- Kernel 1: fused QKV projection ----------------
// o-tile 64 x n-tile 256 per block; 8x8 register blocking per thread.
// Outputs bf16: Q[b][n][32], K[b][m][32], V[b][c][m].
__global__ __launch_bounds__(256) void qkv_proj(
    const float* __restrict__ x,
    const float* __restrict__ wq, const float* __restrict__ bq,
    const float* __restrict__ wk, const float* __restrict__ bk,
    const float* __restrict__ wv, const float* __restrict__ bv,
    u16* __restrict__ Qo, u16* __restrict__ Ko, u16* __restrict__ Vo)
{
  const int ot = blockIdx.x;   // 0..4   (o tile of 64; tile 0 = q|k, 1..4 = v)
  const int nt = blockIdx.y;   // 0..15  (n tile of 256)
  const int b  = blockIdx.z;
  const int o0 = ot * 64;
  const int n0 = nt * 256;
  const int tid = threadIdx.x;
  const int to = tid >> 5;     // 0..7
  const int tn = tid & 31;     // 0..31

  __shared__ float xs[32][256];
  __shared__ float wsm[32][64];

  float acc[8][8];
#pragma unroll
  for (int i = 0; i < 8; i++)
#pragma unroll
    for (int j = 0; j < 8; j++) acc[i][j] = 0.f;

  const int o_l = tid & 63;
  const int cp  = (tid >> 6) * 8;
  const int og  = o0 + o_l;
  const float* wrow = (og < 32) ? (wq + og * CCH)
                    : (og < 64) ? (wk + (og - 32) * CCH)
                                : (wv + (og - 64) * CCH);
  const float* xb = x + ((size_t)b * CCH) * NTOK + n0;

  for (int cc = 0; cc < CCH; cc += 32) {
    __syncthreads();
#pragma unroll
    for (int r = 0; r < 8; r++) {
      int flat = r * 256 + tid;           // float4 index, 2048 total
      int c  = flat >> 6;                 // 0..31
      int nn = (flat & 63) << 2;          // 0..252
      *(float4*)&xs[c][nn] = *(const float4*)(xb + (size_t)(cc + c) * NTOK + nn);
    }
    {
      float4 wa = *(const float4*)(wrow + cc + cp);
      float4 wb = *(const float4*)(wrow + cc + cp + 4);
      wsm[cp + 0][o_l] = wa.x; wsm[cp + 1][o_l] = wa.y;
      wsm[cp + 2][o_l] = wa.z; wsm[cp + 3][o_l] = wa.w;
      wsm[cp + 4][o_l] = wb.x; wsm[cp + 5][o_l] = wb.y;
      wsm[cp + 6][o_l] = wb.z; wsm[cp + 7][o_l] = wb.w;
    }
    __syncthreads();
#pragma unroll
    for (int c = 0; c < 32; c++) {
      float4 w0 = *(float4*)&wsm[c][to * 8];
      float4 w1 = *(float4*)&wsm[c][to * 8 + 4];
      float4 x0 = *(float4*)&xs[c][tn * 8];
      float4 x1 = *(float4*)&xs[c][tn * 8 + 4];
      float wv8[8] = {w0.x, w0.y, w0.z, w0.w, w1.x, w1.y, w1.z, w1.w};
      float xv8[8] = {x0.x, x0.y, x0.z, x0.w, x1.x, x1.y, x1.z, x1.w};
#pragma unroll
      for (int i = 0; i < 8; i++)
#pragma unroll
        for (int j = 0; j < 8; j++) acc[i][j] += wv8[i] * xv8[j];
    }
  }

  float bias[8];
#pragma unroll
  for (int i = 0; i < 8; i++) {
    int o = o0 + to * 8 + i;
    bias[i] = (o < 32) ? bq[o] : (o < 64) ? bk[o - 32] : bv[o - 64];
  }

  if (ot == 0) {
    const int loc = to * 8;   // 0..56; <32 -> q rows, >=32 -> k rows
#pragma unroll
    for (int j = 0; j < 8; j++) {
      int n = n0 + tn * 8 + j;
      uint4 pk;
      pk.x = f2bf2(acc[0][j] + bias[0], acc[1][j] + bias[1]);
      pk.y = f2bf2(acc[2][j] + bias[2], acc[3][j] + bias[3]);
      pk.z = f2bf2(acc[4][j] + bias[4], acc[5][j] + bias[5]);
      pk.w = f2bf2(acc[6][j] + bias[6], acc[7][j] + bias[7]);
      if (loc < 32)
        *(uint4*)(Qo + ((size_t)b * NTOK + n) * CQK + loc) = pk;
      else
        *(uint4*)(Ko + ((size_t)b * NTOK + n) * CQK + (loc - 32)) = pk;
    }
  } else {
    const int cb = (ot - 1) * 64 + to * 8;
#pragma unroll
    for (int i = 0; i < 8; i++) {
      uint4 pk;
      pk.x = f2bf2(acc[i][0] + bias[i], acc[i][1] + bias[i]);
      pk.y = f2bf2(acc[i][2] + bias[i], acc[i][3] + bias[i]);
      pk.z = f2bf2(acc[i][4] + bias[i], acc[i][5] + bias[i]);
      pk.w = f2bf2(acc[i][6] + bias[i], acc[i][7] + bias[i]);
      *(uint4*)(Vo + ((size_t)b * CCH + cb + i) * NTOK + n0 + tn * 8) = pk;
    }
  }
}

// ---------------- Kernel 2: flash attention + residual ----------------
// Block: 512 thr (8 waves), 64 queries. Waves 0-3: S^T + online softmax for
// 16 queries each; all waves: PV over a private 32-channel slice.
__global__ __launch_bounds__(512) void attn(
    const float* __restrict__ x,
    const u16* __restrict__ Qm, const u16* __restrict__ Km,
    const u16* __restrict__ Vm, float* __restrict__ out)
{
  // XCD swizzle: batch b lands on XCDs {2b, 2b+1} -> V panel (2MB) fits L2.
  const int g   = blockIdx.x;
  const int lw3 = g & 7;
  const int b   = lw3 >> 1;
  const int qt  = ((g >> 3) << 1) | (lw3 & 1);
  const int q0  = qt * 64;

  const int tid  = threadIdx.x;
  const int w    = tid >> 6;
  const int lane = tid & 63;
  const int lo   = lane & 15;
  const int hi   = lane >> 4;

  __shared__ u16   P_lds[2][64][72];     // padded stride 72 vs 64: bank spread
  __shared__ float scale_lds[2][64];

  const f32x4 fzero = {0.f, 0.f, 0.f, 0.f};
  constexpr float LOG2E = 1.4426950408889634f;

  // Q fragment (B-operand of S^T mfma): row = query, 8 contiguous d.
  bf16x8 qf = *(const bf16x8*)(Qm + ((size_t)b * NTOK + q0 + (w & 3) * 16 + lo) * CQK + hi * 8);

  f32x4 acc[4][2];
#pragma unroll
  for (int t = 0; t < 4; t++)
#pragma unroll
    for (int cj = 0; cj < 2; cj++) acc[t][cj] = fzero;

  float m_run = -INFINITY, l_run = 0.f;
  const int  c0 = w * 32;
  const u16* Vb = Vm + (size_t)b * CCH * NTOK;
  const u16* Kb = Km + (size_t)b * NTOK * CQK;

  for (int ch = 0; ch < 64; ch++) {
    const int m0  = ch * 64;
    const int buf = ch & 1;

    // Prefetch V fragments (drain at the barrier = free prefetch).
    bf16x8 vf[2][2];
#pragma unroll
    for (int cj = 0; cj < 2; cj++)
#pragma unroll
      for (int mh = 0; mh < 2; mh++)
        vf[cj][mh] = *(const bf16x8*)(Vb + (size_t)(c0 + cj * 16 + lo) * NTOK + m0 + mh * 32 + hi * 8);

    if (w < 4) {
      // S^T[m, n] = sum_d K[m,d] Q[n,d]; lane: n = lo (fixed), m = 16*mt+4*hi+r
      f32x4 s[4];
#pragma unroll
      for (int mt = 0; mt < 4; mt++) {
        bf16x8 kf = *(const bf16x8*)(Kb + (size_t)(m0 + mt * 16 + lo) * CQK + hi * 8);
        s[mt] = mfma16(kf, qf, fzero);
      }
      float cm = -INFINITY;
#pragma unroll
      for (int mt = 0; mt < 4; mt++)
#pragma unroll
        for (int r = 0; r < 4; r++) cm = fmaxf(cm, s[mt][r]);
      cm = fmaxf(cm, __shfl_xor(cm, 16));
      cm = fmaxf(cm, __shfl_xor(cm, 32));
      float mnew  = fmaxf(m_run, cm);
      float alpha = exp2f((m_run - mnew) * LOG2E);
      float ps = 0.f;
      unsigned int pw[4][2];
#pragma unroll
      for (int mt = 0; mt < 4; mt++) {
        float p0 = exp2f((s[mt][0] - mnew) * LOG2E);
        float p1 = exp2f((s[mt][1] - mnew) * LOG2E);
        float p2 = exp2f((s[mt][2] - mnew) * LOG2E);
        float p3 = exp2f((s[mt][3] - mnew) * LOG2E);
        ps += (p0 + p1) + (p2 + p3);
        pw[mt][0] = f2bf2(p0, p1);
        pw[mt][1] = f2bf2(p2, p3);
      }
      ps += __shfl_xor(ps, 16);
      ps += __shfl_xor(ps, 32);
      l_run = l_run * alpha + ps;
      m_run = mnew;
      u16* prow = &P_lds[buf][w * 16 + lo][0];
#pragma unroll
      for (int mt = 0; mt < 4; mt++) {
        *(unsigned int*)(prow + mt * 16 + hi * 4)     = pw[mt][0];
        *(unsigned int*)(prow + mt * 16 + hi * 4 + 2) = pw[mt][1];
      }
      if (lane < 16) scale_lds[buf][w * 16 + lane] = alpha;
    }
    __syncthreads();

    // Rescale accumulators by per-query alpha (D row = query = 4*hi+r).
#pragma unroll
    for (int t = 0; t < 4; t++) {
      float a0 = scale_lds[buf][t * 16 + hi * 4 + 0];
      float a1 = scale_lds[buf][t * 16 + hi * 4 + 1];
      float a2 = scale_lds[buf][t * 16 + hi * 4 + 2];
      float a3 = scale_lds[buf][t * 16 + hi * 4 + 3];
#pragma unroll
      for (int cj = 0; cj < 2; cj++) {
        acc[t][cj][0] *= a0; acc[t][cj][1] *= a1;
        acc[t][cj][2] *= a2; acc[t][cj][3] *= a3;
      }
    }
    // PV: O[n, c] += P[n, m] * V[c, m]
    bf16x8 af[4][2];
#pragma unroll
    for (int t = 0; t < 4; t++)
#pragma unroll
      for (int mh = 0; mh < 2; mh++)
        af[t][mh] = *(const bf16x8*)(&P_lds[buf][t * 16 + lo][mh * 32 + hi * 8]);
#pragma unroll
    for (int t = 0; t < 4; t++)
#pragma unroll
      for (int cj = 0; cj < 2; cj++)
#pragma unroll
        for (int mh = 0; mh < 2; mh++)
          acc[t][cj] = mfma16(af[t][mh], vf[cj][mh], acc[t][cj]);
  }

  // Final normalization + residual.
  if (w < 4 && lane < 16) scale_lds[0][w * 16 + lane] = l_run;
  __syncthreads();

  const float* xb = x   + (size_t)b * CCH * NTOK;
  float*       ob = out + (size_t)b * CCH * NTOK;
#pragma unroll
  for (int t = 0; t < 4; t++) {
    float il0 = 1.f / scale_lds[0][t * 16 + hi * 4 + 0];
    float il1 = 1.f / scale_lds[0][t * 16 + hi * 4 + 1];
    float il2 = 1.f / scale_lds[0][t * 16 + hi * 4 + 2];
    float il3 = 1.f / scale_lds[0][t * 16 + hi * 4 + 3];
#pragma unroll
    for (int cj = 0; cj < 2; cj++) {
      int c = c0 + cj * 16 + lo;
      size_t base = (size_t)c * NTOK + q0 + t * 16 + hi * 4;
      ob[base + 0] = acc[t][cj][0] * il0 + xb[base + 0];
      ob[base + 1] = acc[t][cj][1] * il1 + xb[base + 1];
      ob[base + 2] = acc[t][cj][2] * il2 + xb[base + 2];
      ob[base + 3] = acc[t][cj][3] * il3 + xb[base + 3];
    }
  }
}

extern "C" void kernel_launch(void* const* d_in, const int* in_sizes, int n_in,
                              void* d_out, int out_size, void* d_ws, size_t ws_size,
                              hipStream_t stream) {
  const float* x  = (const float*)d_in[0];
  const float* wq = (const float*)d_in[1];
  const float* bq = (const float*)d_in[2];
  const float* wk = (const float*)d_in[3];
  const float* bk = (const float*)d_in[4];
  const float* wv = (const float*)d_in[5];
  const float* bv = (const float*)d_in[6];
  float* out = (float*)d_out;

  // Workspace layout (bf16): Q [4,4096,32], K [4,4096,32], V [4,256,4096]
  u16* Qp = (u16*)d_ws;
  u16* Kp = Qp + (size_t)NB * NTOK * CQK;
  u16* Vp = Kp + (size_t)NB * NTOK * CQK;

  dim3 pgrid(5, 16, NB);
  qkv_proj<<<pgrid, 256, 0, stream>>>(x, wq, bq, wk, bk, wv, bv, Qp, Kp, Vp);
  attn<<<256, 512, 0, stream>>>(x, Qp, Kp, Vp, out);
}

// Round 2
// 157.781 us; speedup vs baseline: 1.2839x; 1.2839x over previous
//
#include <hip/hip_runtime.h>
#include <hip/hip_bf16.h>

#define NB   4
#define CCH  256
#define CQK  32
#define NTOK 4096

typedef unsigned short u16;
typedef __attribute__((ext_vector_type(8))) __bf16 bf16x8;
typedef __attribute__((ext_vector_type(4))) float  f32x4;

static __device__ __forceinline__ unsigned int f2bf2(float a, float b) {
  union { __hip_bfloat162 h; unsigned int u; } cv;
  cv.h = __float22bfloat162_rn(make_float2(a, b));
  return cv.u;
}

static __device__ __forceinline__ f32x4 mfma16(bf16x8 a, bf16x8 b, f32x4 c) {
  return __builtin_amdgcn_mfma_f32_16x16x32_bf16(a, b, c, 0, 0, 0);
}

// ---------------- Kernel 1: fused QKV projection ----------------
// o-tile 64 x n-tile 256 per block; 8x8 register blocking per thread.
// Outputs bf16: Q[b][n][32] (pre-scaled by log2(e)), K[b][m][32], V[b][c][m].
__global__ __launch_bounds__(256) void qkv_proj(
    const float* __restrict__ x,
    const float* __restrict__ wq, const float* __restrict__ bq,
    const float* __restrict__ wk, const float* __restrict__ bk,
    const float* __restrict__ wv, const float* __restrict__ bv,
    u16* __restrict__ Qo, u16* __restrict__ Ko, u16* __restrict__ Vo)
{
  const int ot = blockIdx.x;   // 0..4   (o tile of 64; tile 0 = q|k, 1..4 = v)
  const int nt = blockIdx.y;   // 0..15  (n tile of 256)
  const int b  = blockIdx.z;
  const int o0 = ot * 64;
  const int n0 = nt * 256;
  const int tid = threadIdx.x;
  const int to = tid >> 5;     // 0..7
  const int tn = tid & 31;     // 0..31

  __shared__ float xs[32][256];
  __shared__ float wsm[32][64];

  float acc[8][8];
#pragma unroll
  for (int i = 0; i < 8; i++)
#pragma unroll
    for (int j = 0; j < 8; j++) acc[i][j] = 0.f;

  const int o_l = tid & 63;
  const int cp  = (tid >> 6) * 8;
  const int og  = o0 + o_l;
  const float* wrow = (og < 32) ? (wq + og * CCH)
                    : (og < 64) ? (wk + (og - 32) * CCH)
                                : (wv + (og - 64) * CCH);
  const float* xb = x + ((size_t)b * CCH) * NTOK + n0;

  for (int cc = 0; cc < CCH; cc += 32) {
    __syncthreads();
#pragma unroll
    for (int r = 0; r < 8; r++) {
      int flat = r * 256 + tid;           // float4 index, 2048 total
      int c  = flat >> 6;                 // 0..31
      int nn = (flat & 63) << 2;          // 0..252
      *(float4*)&xs[c][nn] = *(const float4*)(xb + (size_t)(cc + c) * NTOK + nn);
    }
    {
      float4 wa = *(const float4*)(wrow + cc + cp);
      float4 wb = *(const float4*)(wrow + cc + cp + 4);
      wsm[cp + 0][o_l] = wa.x; wsm[cp + 1][o_l] = wa.y;
      wsm[cp + 2][o_l] = wa.z; wsm[cp + 3][o_l] = wa.w;
      wsm[cp + 4][o_l] = wb.x; wsm[cp + 5][o_l] = wb.y;
      wsm[cp + 6][o_l] = wb.z; wsm[cp + 7][o_l] = wb.w;
    }
    __syncthreads();
#pragma unroll
    for (int c = 0; c < 32; c++) {
      float4 w0 = *(float4*)&wsm[c][to * 8];
      float4 w1 = *(float4*)&wsm[c][to * 8 + 4];
      float4 x0 = *(float4*)&xs[c][tn * 8];
      float4 x1 = *(float4*)&xs[c][tn * 8 + 4];
      float wv8[8] = {w0.x, w0.y, w0.z, w0.w, w1.x, w1.y, w1.z, w1.w};
      float xv8[8] = {x0.x, x0.y, x0.z, x0.w, x1.x, x1.y, x1.z, x1.w};
#pragma unroll
      for (int i = 0; i < 8; i++)
#pragma unroll
        for (int j = 0; j < 8; j++) acc[i][j] += wv8[i] * xv8[j];
    }
  }

  float bias[8];
#pragma unroll
  for (int i = 0; i < 8; i++) {
    int o = o0 + to * 8 + i;
    bias[i] = (o < 32) ? bq[o] : (o < 64) ? bk[o - 32] : bv[o - 64];
  }

  if (ot == 0) {
    const int loc = to * 8;   // 0..56; <32 -> q rows, >=32 -> k rows
    // Q pre-scaled by log2(e) so attn softmax runs natively in exp2 domain.
    const float qs = (loc < 32) ? 1.4426950408889634f : 1.0f;
#pragma unroll
    for (int j = 0; j < 8; j++) {
      int n = n0 + tn * 8 + j;
      uint4 pk;
      pk.x = f2bf2((acc[0][j] + bias[0]) * qs, (acc[1][j] + bias[1]) * qs);
      pk.y = f2bf2((acc[2][j] + bias[2]) * qs, (acc[3][j] + bias[3]) * qs);
      pk.z = f2bf2((acc[4][j] + bias[4]) * qs, (acc[5][j] + bias[5]) * qs);
      pk.w = f2bf2((acc[6][j] + bias[6]) * qs, (acc[7][j] + bias[7]) * qs);
      if (loc < 32)
        *(uint4*)(Qo + ((size_t)b * NTOK + n) * CQK + loc) = pk;
      else
        *(uint4*)(Ko + ((size_t)b * NTOK + n) * CQK + (loc - 32)) = pk;
    }
  } else {
    const int cb = (ot - 1) * 64 + to * 8;
#pragma unroll
    for (int i = 0; i < 8; i++) {
      uint4 pk;
      pk.x = f2bf2(acc[i][0] + bias[i], acc[i][1] + bias[i]);
      pk.y = f2bf2(acc[i][2] + bias[i], acc[i][3] + bias[i]);
      pk.z = f2bf2(acc[i][4] + bias[i], acc[i][5] + bias[i]);
      pk.w = f2bf2(acc[i][6] + bias[i], acc[i][7] + bias[i]);
      *(uint4*)(Vo + ((size_t)b * CCH + cb + i) * NTOK + n0 + tn * 8) = pk;
    }
  }
}

// ---------------- Kernel 2: pipelined flash attention + residual ----------------
// Block: 512 thr (8 waves), 64 queries, grid 256 (1 block/CU).
// Pipeline: iter i computes softmax(chunk i+1) (waves 0-3, VALU) overlapped
// with PV(chunk i) (all 8 waves, MFMA). One barrier per chunk. K fragments
// register-double-buffered two chunks ahead.
__global__ __launch_bounds__(512, 2) void attn(
    const float* __restrict__ x,
    const u16* __restrict__ Qm, const u16* __restrict__ Km,
    const u16* __restrict__ Vm, float* __restrict__ out)
{
  // XCD swizzle: batch b lands on XCDs {2b, 2b+1} -> V panel (2MB) fits L2.
  const int g   = blockIdx.x;
  const int lw3 = g & 7;
  const int b   = lw3 >> 1;
  const int qt  = ((g >> 3) << 1) | (lw3 & 1);
  const int q0  = qt * 64;

  const int tid  = threadIdx.x;
  const int w    = tid >> 6;
  const int lane = tid & 63;
  const int lo   = lane & 15;
  const int hi   = lane >> 4;

  __shared__ u16   P_lds[2][64][72];
  __shared__ float scale_lds[2][64];

  const f32x4 fzero = {0.f, 0.f, 0.f, 0.f};

  // Q fragment (B-operand of S^T mfma): row = query, 8 contiguous d.
  bf16x8 qf = *(const bf16x8*)(Qm + ((size_t)b * NTOK + q0 + (w & 3) * 16 + lo) * CQK + hi * 8);

  f32x4 acc[4][2];
#pragma unroll
  for (int t = 0; t < 4; t++)
#pragma unroll
    for (int cj = 0; cj < 2; cj++) acc[t][cj] = fzero;

  float m_run = -INFINITY, l_run = 0.f;
  const int  c0 = w * 32;
  const u16* Vb = Vm + (size_t)b * CCH * NTOK;
  const u16* Kb = Km + (size_t)b * NTOK * CQK;

  bf16x8 kf_cur[4], kf_nxt[4];

  // softmax for the chunk whose K frags sit in kf_cur; P/alpha -> buffer nb.
  auto softmax_chunk = [&](int nb) {
    f32x4 s[4];
#pragma unroll
    for (int mt = 0; mt < 4; mt++) s[mt] = mfma16(kf_cur[mt], qf, fzero);
    float cm = -INFINITY;
#pragma unroll
    for (int mt = 0; mt < 4; mt++)
#pragma unroll
      for (int r = 0; r < 4; r++) cm = fmaxf(cm, s[mt][r]);
    cm = fmaxf(cm, __shfl_xor(cm, 16));
    cm = fmaxf(cm, __shfl_xor(cm, 32));
    float mnew  = fmaxf(m_run, cm);
    float alpha = __builtin_amdgcn_exp2f(m_run - mnew);
    float ps = 0.f;
    unsigned int pw[4][2];
#pragma unroll
    for (int mt = 0; mt < 4; mt++) {
      float p0 = __builtin_amdgcn_exp2f(s[mt][0] - mnew);
      float p1 = __builtin_amdgcn_exp2f(s[mt][1] - mnew);
      float p2 = __builtin_amdgcn_exp2f(s[mt][2] - mnew);
      float p3 = __builtin_amdgcn_exp2f(s[mt][3] - mnew);
      ps += (p0 + p1) + (p2 + p3);
      pw[mt][0] = f2bf2(p0, p1);
      pw[mt][1] = f2bf2(p2, p3);
    }
    ps += __shfl_xor(ps, 16);
    ps += __shfl_xor(ps, 32);
    l_run = l_run * alpha + ps;
    m_run = mnew;
    u16* prow = &P_lds[nb][w * 16 + lo][0];
#pragma unroll
    for (int mt = 0; mt < 4; mt++) {
      *(unsigned int*)(prow + mt * 16 + hi * 4)     = pw[mt][0];
      *(unsigned int*)(prow + mt * 16 + hi * 4 + 2) = pw[mt][1];
    }
    if (lane < 16) scale_lds[nb][w * 16 + lane] = alpha;
  };

  // Prologue: softmax for chunk 0 into buf 0; prefetch K for chunk 1.
  if (w < 4) {
#pragma unroll
    for (int mt = 0; mt < 4; mt++)
      kf_cur[mt] = *(const bf16x8*)(Kb + (size_t)(mt * 16 + lo) * CQK + hi * 8);
    softmax_chunk(0);
#pragma unroll
    for (int mt = 0; mt < 4; mt++)
      kf_cur[mt] = *(const bf16x8*)(Kb + (size_t)(64 + mt * 16 + lo) * CQK + hi * 8);
  }
  __syncthreads();

  for (int ch = 0; ch < 64; ch++) {
    const int buf  = ch & 1;
    const int nbuf = buf ^ 1;
    const int m0   = ch * 64;

    // V fragments for the current chunk (consumed at end of iter: hidden).
    bf16x8 vf[2][2];
#pragma unroll
    for (int cj = 0; cj < 2; cj++)
#pragma unroll
      for (int mh = 0; mh < 2; mh++)
        vf[cj][mh] = *(const bf16x8*)(Vb + (size_t)(c0 + cj * 16 + lo) * NTOK + m0 + mh * 32 + hi * 8);

    // K fragments two chunks ahead.
    if (w < 4 && ch + 2 < 64) {
#pragma unroll
      for (int mt = 0; mt < 4; mt++)
        kf_nxt[mt] = *(const bf16x8*)(Kb + (size_t)((ch + 2) * 64 + mt * 16 + lo) * CQK + hi * 8);
    }

    // Issue LDS reads for PV(ch) early; latency hides under softmax VALU.
    f32x4 al[4];
#pragma unroll
    for (int t = 0; t < 4; t++) al[t] = *(f32x4*)&scale_lds[buf][t * 16 + hi * 4];
    bf16x8 af[4][2];
#pragma unroll
    for (int t = 0; t < 4; t++)
#pragma unroll
      for (int mh = 0; mh < 2; mh++)
        af[t][mh] = *(const bf16x8*)(&P_lds[buf][t * 16 + lo][mh * 32 + hi * 8]);

    // Softmax for chunk ch+1 (waves 0-3, VALU) — independent of PV(ch).
    if (w < 4 && ch + 1 < 64) softmax_chunk(nbuf);

    // Rescale accumulators by per-query alpha(ch), then PV(ch).
#pragma unroll
    for (int t = 0; t < 4; t++)
#pragma unroll
      for (int cj = 0; cj < 2; cj++) {
        acc[t][cj][0] *= al[t][0]; acc[t][cj][1] *= al[t][1];
        acc[t][cj][2] *= al[t][2]; acc[t][cj][3] *= al[t][3];
      }
#pragma unroll
    for (int t = 0; t < 4; t++)
#pragma unroll
      for (int cj = 0; cj < 2; cj++)
#pragma unroll
        for (int mh = 0; mh < 2; mh++)
          acc[t][cj] = mfma16(af[t][mh], vf[cj][mh], acc[t][cj]);

    if (w < 4) {
#pragma unroll
      for (int mt = 0; mt < 4; mt++) kf_cur[mt] = kf_nxt[mt];
    }
    __syncthreads();
  }

  // Final normalization + residual.
  if (w < 4 && lane < 16) scale_lds[0][w * 16 + lane] = l_run;
  __syncthreads();

  const float* xb = x   + (size_t)b * CCH * NTOK;
  float*       ob = out + (size_t)b * CCH * NTOK;
#pragma unroll
  for (int t = 0; t < 4; t++) {
    float il0 = 1.f / scale_lds[0][t * 16 + hi * 4 + 0];
    float il1 = 1.f / scale_lds[0][t * 16 + hi * 4 + 1];
    float il2 = 1.f / scale_lds[0][t * 16 + hi * 4 + 2];
    float il3 = 1.f / scale_lds[0][t * 16 + hi * 4 + 3];
#pragma unroll
    for (int cj = 0; cj < 2; cj++) {
      int c = c0 + cj * 16 + lo;
      size_t base = (size_t)c * NTOK + q0 + t * 16 + hi * 4;
      ob[base + 0] = acc[t][cj][0] * il0 + xb[base + 0];
      ob[base + 1] = acc[t][cj][1] * il1 + xb[base + 1];
      ob[base + 2] = acc[t][cj][2] * il2 + xb[base + 2];
      ob[base + 3] = acc[t][cj][3] * il3 + xb[base + 3];
    }
  }
}

extern "C" void kernel_launch(void* const* d_in, const int* in_sizes, int n_in,
                              void* d_out, int out_size, void* d_ws, size_t ws_size,
                              hipStream_t stream) {
  const float* x  = (const float*)d_in[0];
  const float* wq = (const float*)d_in[1];
  const float* bq = (const float*)d_in[2];
  const float* wk = (const float*)d_in[3];
  const float* bk = (const float*)d_in[4];
  const float* wv = (const float*)d_in[5];
  const float* bv = (const float*)d_in[6];
  float* out = (float*)d_out;

  // Workspace layout (bf16): Q [4,4096,32], K [4,4096,32], V [4,256,4096]
  u16* Qp = (u16*)d_ws;
  u16* Kp = Qp + (size_t)NB * NTOK * CQK;
  u16* Vp = Kp + (size_t)NB * NTOK * CQK;

  dim3 pgrid(5, 16, NB);
  qkv_proj<<<pgrid, 256, 0, stream>>>(x, wq, bq, wk, bk, wv, bv, Qp, Kp, Vp);
  attn<<<256, 512, 0, stream>>>(x, Qp, Kp, Vp, out);
}